// Round 1
// baseline (1021.282 us; speedup 1.0000x reference)
//
#include <hip/hip_runtime.h>
#include <hip/hip_bf16.h>
#include <cstdint>
#include <cstddef>

// Problem constants
#define NN     20000     // nodes
#define NF     128       // in features
#define NH     56        // heads
#define OC     32        // out channels per head
#define DD1    1792      // NH*OC
#define NE     100000    // edges (before self loops)
#define ETOT   120000    // edges + self loops
#define NG     50        // graphs
#define EPS_BN 1e-5f

typedef __bf16 bf16x8 __attribute__((ext_vector_type(8)));
typedef float  floatx4 __attribute__((ext_vector_type(4)));
typedef unsigned int u32;
typedef __attribute__((address_space(1))) u32 gu32;
typedef __attribute__((address_space(3))) u32 lu32;

__device__ __forceinline__ void async_copy16(void* lds, const void* g) {
    __builtin_amdgcn_global_load_lds((gu32*)const_cast<void*>(g), (lu32*)lds, 16, 0, 0);
}

// ---------------- elementwise cast fp32 -> bf16 ----------------
__global__ __launch_bounds__(256) void cast_bf16_kernel(const float* __restrict__ in,
                                                        __hip_bfloat16* __restrict__ out, int n) {
    int i = blockIdx.x * 256 + threadIdx.x;
    if (i < n) out[i] = __float2bfloat16(in[i]);
}

// ---------------- tiled transpose + cast: in[R][C] f32 -> out[C][R] bf16 ----------------
__global__ __launch_bounds__(256) void transpose_cast_kernel(const float* __restrict__ in,
                                                             __hip_bfloat16* __restrict__ out,
                                                             int R, int C) {
    __shared__ float tile[32][33];
    int c0 = blockIdx.x * 32, r0 = blockIdx.y * 32;
    int tx = threadIdx.x & 31, ty = threadIdx.x >> 5;   // ty in 0..7
    #pragma unroll
    for (int i = 0; i < 32; i += 8) {
        int r = r0 + ty + i, c = c0 + tx;
        if (r < R && c < C) tile[ty + i][tx] = in[(size_t)r * C + c];
    }
    __syncthreads();
    #pragma unroll
    for (int i = 0; i < 32; i += 8) {
        int c = c0 + ty + i, r = r0 + tx;
        if (c < C && r < R) out[(size_t)c * R + r] = __float2bfloat16(tile[tx][ty + i]);
    }
}

// ---------------- CSR build: histogram / scan / scatter ----------------
__global__ __launch_bounds__(256) void hist_kernel(const int* __restrict__ ei, int* __restrict__ deg) {
    int i = blockIdx.x * 256 + threadIdx.x;
    if (i >= ETOT) return;
    int dst = (i < NE) ? ei[NE + i] : (i - NE);
    atomicAdd(&deg[dst], 1);
}

__global__ __launch_bounds__(1024) void scan_kernel(const int* __restrict__ deg,
                                                    int* __restrict__ rowptr,
                                                    int* __restrict__ cursor) {
    __shared__ int buf[1024];
    int t = threadIdx.x;
    const int CH = (NN + 1023) >> 10;   // 20
    int base = t * CH;
    int s = 0;
    for (int j = 0; j < CH; ++j) { int idx = base + j; if (idx < NN) s += deg[idx]; }
    buf[t] = s;
    __syncthreads();
    for (int off = 1; off < 1024; off <<= 1) {
        int v = (t >= off) ? buf[t - off] : 0;
        __syncthreads();
        buf[t] += v;
        __syncthreads();
    }
    int run = buf[t] - s;   // exclusive
    for (int j = 0; j < CH; ++j) {
        int idx = base + j;
        if (idx < NN) { rowptr[idx] = run; cursor[idx] = run; run += deg[idx]; }
    }
    if (t == 1023) rowptr[NN] = buf[1023];
}

__global__ __launch_bounds__(256) void scatter_kernel(const int* __restrict__ ei,
                                                      int* __restrict__ cursor,
                                                      int* __restrict__ csr_src) {
    int i = blockIdx.x * 256 + threadIdx.x;
    if (i >= ETOT) return;
    int s, d;
    if (i < NE) { s = ei[i]; d = ei[NE + i]; } else { s = i - NE; d = i - NE; }
    int pos = atomicAdd(&cursor[d], 1);
    csr_src[pos] = s;
}

// ---------------- bf16 MFMA GEMM: C[M][N] = A[M][K] * Bt[N][K]^T, bf16 out ----------------
// 128x128 tile, BK=32, 4 waves in 2x2, each wave 64x64 via 4x4 mfma_f32_16x16x32_bf16.
__global__ __launch_bounds__(256) void gemm_bf16(const __hip_bfloat16* __restrict__ A,
                                                 const __hip_bfloat16* __restrict__ Bt,
                                                 __hip_bfloat16* __restrict__ C,
                                                 int M, int N, int K) {
    __shared__ __align__(16) unsigned short lsA[128 * 32];
    __shared__ __align__(16) unsigned short lsB[128 * 32];
    const int tid  = threadIdx.x;
    const int lane = tid & 63, wave = tid >> 6;
    const int wm = wave >> 1, wn = wave & 1;
    const int m0 = blockIdx.y * 128, n0 = blockIdx.x * 128;

    floatx4 zero = {0.f, 0.f, 0.f, 0.f};
    floatx4 acc[4][4];
    #pragma unroll
    for (int i = 0; i < 4; ++i)
        #pragma unroll
        for (int j = 0; j < 4; ++j) acc[i][j] = zero;

    for (int k0 = 0; k0 < K; k0 += 32) {
        // stage A tile [128 rows][32 k] with per-row XOR swizzle of 16B k-segments
        #pragma unroll
        for (int i = 0; i < 2; ++i) {
            int slot = tid + i * 256;
            int row = slot >> 2, seg = slot & 3;
            int gseg = seg ^ ((row >> 1) & 3);
            int gr = m0 + row; if (gr > M - 1) gr = M - 1;
            async_copy16(&lsA[slot * 8], A + (size_t)gr * K + k0 + gseg * 8);
        }
        #pragma unroll
        for (int i = 0; i < 2; ++i) {
            int slot = tid + i * 256;
            int row = slot >> 2, seg = slot & 3;
            int gseg = seg ^ ((row >> 1) & 3);
            async_copy16(&lsB[slot * 8], Bt + (size_t)(n0 + row) * K + k0 + gseg * 8);
        }
        __syncthreads();

        bf16x8 aF[4], bF[4];
        const int q = lane >> 4;            // k-segment 0..3
        #pragma unroll
        for (int mt = 0; mt < 4; ++mt) {
            int row = wm * 64 + mt * 16 + (lane & 15);
            int seg = q ^ ((row >> 1) & 3);
            aF[mt] = *(const bf16x8*)&lsA[row * 32 + seg * 8];
        }
        #pragma unroll
        for (int nt = 0; nt < 4; ++nt) {
            int row = wn * 64 + nt * 16 + (lane & 15);
            int seg = q ^ ((row >> 1) & 3);
            bF[nt] = *(const bf16x8*)&lsB[row * 32 + seg * 8];
        }
        #pragma unroll
        for (int mt = 0; mt < 4; ++mt)
            #pragma unroll
            for (int nt = 0; nt < 4; ++nt)
                acc[mt][nt] = __builtin_amdgcn_mfma_f32_16x16x32_bf16(aF[mt], bF[nt], acc[mt][nt], 0, 0, 0);
        __syncthreads();
    }

    // epilogue: C/D layout col=lane&15, row=(lane>>4)*4+r
    #pragma unroll
    for (int mt = 0; mt < 4; ++mt) {
        #pragma unroll
        for (int r = 0; r < 4; ++r) {
            int rowc = m0 + wm * 64 + mt * 16 + (lane >> 4) * 4 + r;
            if (rowc < M) {
                #pragma unroll
                for (int nt = 0; nt < 4; ++nt) {
                    int col = n0 + wn * 64 + nt * 16 + (lane & 15);
                    C[(size_t)rowc * N + col] = __float2bfloat16(acc[mt][nt][r]);
                }
            }
        }
    }
}

// ---------------- attention scores: as/ad[n,h] = sum_o h[n,h,o]*att[h,o] ----------------
__global__ __launch_bounds__(256) void attn_score(const __hip_bfloat16* __restrict__ h,
                                                  const float* __restrict__ att_src,
                                                  const float* __restrict__ att_dst,
                                                  float* __restrict__ as_,
                                                  float* __restrict__ ad_) {
    int wave = threadIdx.x >> 6, lane = threadIdx.x & 63;
    int node = blockIdx.x * 4 + wave;
    if (node >= NN || lane >= NH) return;
    const bf16x8* hp = (const bf16x8*)(h + (size_t)node * DD1 + lane * OC);
    float s = 0.f, d = 0.f;
    #pragma unroll
    for (int jj = 0; jj < 4; ++jj) {
        bf16x8 hv = hp[jj];
        #pragma unroll
        for (int j = 0; j < 8; ++j) {
            float v = (float)hv[j];
            int o = jj * 8 + j;
            s += v * att_src[lane * OC + o];
            d += v * att_dst[lane * OC + o];
        }
    }
    as_[node * NH + lane] = s;
    ad_[node * NH + lane] = d;
}

// ---------------- per-dst attention aggregation (one block per node) ----------------
// LAYER==1: out = bf16 h1p[n][1792] = BN1(ELU(agg + b1))
// LAYER==2: out = f32  h2s[n][32]   = BN2(mean_heads(agg) + b2)
template <int LAYER>
__global__ __launch_bounds__(256) void attn_aggregate(const int* __restrict__ rowptr,
                                                      const int* __restrict__ csr_src,
                                                      const float* __restrict__ as_,
                                                      const float* __restrict__ ad_,
                                                      const __hip_bfloat16* __restrict__ h,
                                                      const float* __restrict__ bias,
                                                      const float* __restrict__ bng,
                                                      const float* __restrict__ bnb,
                                                      const float* __restrict__ bnm,
                                                      const float* __restrict__ bnv,
                                                      void* __restrict__ outp) {
    __shared__ float ad_l[NH];
    __shared__ float red[4 * NH];
    __shared__ float mh[NH];
    __shared__ float inv_den[NH];
    __shared__ float alpha[NH];
    __shared__ float fin[DD1];

    const int n = blockIdx.x;
    const int t = threadIdx.x;
    const int wave = t >> 6, lane = t & 63;
    const int e0 = rowptr[n], e1 = rowptr[n + 1];

    if (t < NH) ad_l[t] = ad_[n * NH + t];
    __syncthreads();

    // pass A: per-head max of leaky_relu(as[src]+ad[dst])
    if (lane < NH) {
        float mx = -1e30f;
        for (int e = e0 + wave; e < e1; e += 4) {
            int s = csr_src[e];
            float el = as_[s * NH + lane] + ad_l[lane];
            el = el > 0.f ? el : 0.2f * el;
            mx = fmaxf(mx, el);
        }
        red[wave * NH + lane] = mx;
    }
    __syncthreads();
    if (t < NH) mh[t] = fmaxf(fmaxf(red[t], red[NH + t]), fmaxf(red[2 * NH + t], red[3 * NH + t]));
    __syncthreads();

    // pass B: denominator
    if (lane < NH) {
        float sm = 0.f;
        for (int e = e0 + wave; e < e1; e += 4) {
            int s = csr_src[e];
            float el = as_[s * NH + lane] + ad_l[lane];
            el = el > 0.f ? el : 0.2f * el;
            sm += __expf(el - mh[lane]);
        }
        red[wave * NH + lane] = sm;
    }
    __syncthreads();
    if (t < NH) inv_den[t] = 1.f / (red[t] + red[NH + t] + red[2 * NH + t] + red[3 * NH + t]);
    __syncthreads();

    // pass C: out[d] = sum_e alpha[e][d>>5] * h[src_e][d]  (224 threads x 8 contiguous)
    float acc[8];
    #pragma unroll
    for (int j = 0; j < 8; ++j) acc[j] = 0.f;

    for (int e = e0; e < e1; ++e) {
        int s = csr_src[e];
        if (t < NH) {
            float el = as_[s * NH + t] + ad_l[t];
            el = el > 0.f ? el : 0.2f * el;
            alpha[t] = __expf(el - mh[t]) * inv_den[t];
        }
        __syncthreads();
        if (t < 224) {
            bf16x8 hv = *(const bf16x8*)(h + (size_t)s * DD1 + t * 8);
            float a = alpha[t >> 2];   // head = (t*8)>>5
            #pragma unroll
            for (int j = 0; j < 8; ++j) acc[j] += a * (float)hv[j];
        }
        __syncthreads();
    }

    if (LAYER == 1) {
        if (t < 224) {
            __hip_bfloat16* op = (__hip_bfloat16*)outp + (size_t)n * DD1 + t * 8;
            #pragma unroll
            for (int j = 0; j < 8; ++j) {
                int d = t * 8 + j;
                float v = acc[j] + bias[d];
                v = v > 0.f ? v : expm1f(v);                                 // ELU
                v = (v - bnm[d]) * rsqrtf(bnv[d] + EPS_BN) * bng[d] + bnb[d]; // BN1
                op[j] = __float2bfloat16(v);
            }
        }
    } else {
        if (t < 224) {
            #pragma unroll
            for (int j = 0; j < 8; ++j) fin[t * 8 + j] = acc[j];
        }
        __syncthreads();
        if (t < OC) {
            float s = 0.f;
            #pragma unroll
            for (int hh = 0; hh < NH; ++hh) s += fin[hh * OC + t];
            float v = s * (1.f / NH) + bias[t];
            v = (v - bnm[t]) * rsqrtf(bnv[t] + EPS_BN) * bng[t] + bnb[t];    // BN2
            ((float*)outp)[(size_t)n * OC + t] = v;
        }
    }
}

// ---------------- mean pool (atomics) + final linear ----------------
__global__ __launch_bounds__(256) void pool_kernel(const float* __restrict__ h2s,
                                                   const int* __restrict__ batch,
                                                   float* __restrict__ sums,
                                                   float* __restrict__ cnt) {
    int gid = blockIdx.x * 256 + threadIdx.x;
    if (gid >= NN * OC) return;
    int node = gid >> 5, ch = gid & 31;
    int g = batch[node];
    atomicAdd(&sums[g * OC + ch], h2s[gid]);
    if (ch == 0) atomicAdd(&cnt[g], 1.0f);
}

__global__ __launch_bounds__(128) void final_kernel(const float* __restrict__ sums,
                                                    const float* __restrict__ cnt,
                                                    const float* __restrict__ lin_w,
                                                    const float* __restrict__ lin_b,
                                                    float* __restrict__ out) {
    int t = threadIdx.x;
    if (t >= NG * 2) return;
    int g = t >> 1, c = t & 1;
    float invc = 1.f / fmaxf(cnt[g], 1.f);
    float acc = lin_b[c];
    #pragma unroll
    for (int o = 0; o < OC; ++o) acc += sums[g * OC + o] * invc * lin_w[o * 2 + c];
    out[t] = acc;
}

// ---------------- host-side launch ----------------
extern "C" void kernel_launch(void* const* d_in, const int* in_sizes, int n_in,
                              void* d_out, int out_size, void* d_ws, size_t ws_size,
                              hipStream_t stream) {
    const float* x    = (const float*)d_in[0];
    const int*   ei   = (const int*)d_in[1];
    const int*   bat  = (const int*)d_in[2];
    const float* W1   = (const float*)d_in[3];
    const float* at_s1 = (const float*)d_in[4];
    const float* at_d1 = (const float*)d_in[5];
    const float* b1   = (const float*)d_in[6];
    const float* bn1g = (const float*)d_in[7];
    const float* bn1b = (const float*)d_in[8];
    const float* bn1m = (const float*)d_in[9];
    const float* bn1v = (const float*)d_in[10];
    const float* W2   = (const float*)d_in[11];
    const float* at_s2 = (const float*)d_in[12];
    const float* at_d2 = (const float*)d_in[13];
    const float* b2   = (const float*)d_in[14];
    const float* bn2g = (const float*)d_in[15];
    const float* bn2b = (const float*)d_in[16];
    const float* bn2m = (const float*)d_in[17];
    const float* bn2v = (const float*)d_in[18];
    const float* linw = (const float*)d_in[19];
    const float* linb = (const float*)d_in[20];
    float* out = (float*)d_out;

    char* wsp = (char*)d_ws;
    auto alloc = [&](size_t bytes) -> void* {
        void* p = (void*)wsp;
        wsp += (bytes + 255) & ~(size_t)255;
        return p;
    };
    __hip_bfloat16* h1  = (__hip_bfloat16*)alloc((size_t)NN * DD1 * 2);  // also reused as h2
    __hip_bfloat16* h1p = (__hip_bfloat16*)alloc((size_t)NN * DD1 * 2);
    __hip_bfloat16* xb  = (__hip_bfloat16*)alloc((size_t)NN * NF * 2);
    __hip_bfloat16* w1t = (__hip_bfloat16*)alloc((size_t)DD1 * NF * 2);
    __hip_bfloat16* w2t = (__hip_bfloat16*)alloc((size_t)DD1 * DD1 * 2);
    float* asb   = (float*)alloc((size_t)NN * NH * 4);
    float* adb   = (float*)alloc((size_t)NN * NH * 4);
    int*   deg   = (int*)alloc((size_t)NN * 4);
    int*   rowp  = (int*)alloc((size_t)(NN + 1) * 4);
    int*   curs  = (int*)alloc((size_t)NN * 4);
    int*   csr   = (int*)alloc((size_t)ETOT * 4);
    float* h2s   = (float*)alloc((size_t)NN * OC * 4);
    float* sums  = (float*)alloc((size_t)(NG * OC + NG) * 4);
    float* cnt   = sums + NG * OC;

    hipMemsetAsync(deg, 0, (size_t)NN * 4, stream);
    hipMemsetAsync(sums, 0, (size_t)(NG * OC + NG) * 4, stream);

    cast_bf16_kernel<<<(NN * NF + 255) / 256, 256, 0, stream>>>(x, xb, NN * NF);
    transpose_cast_kernel<<<dim3(DD1 / 32, NF / 32), 256, 0, stream>>>(W1, w1t, NF, DD1);
    transpose_cast_kernel<<<dim3(DD1 / 32, DD1 / 32), 256, 0, stream>>>(W2, w2t, DD1, DD1);
    hist_kernel<<<(ETOT + 255) / 256, 256, 0, stream>>>(ei, deg);
    scan_kernel<<<1, 1024, 0, stream>>>(deg, rowp, curs);
    scatter_kernel<<<(ETOT + 255) / 256, 256, 0, stream>>>(ei, curs, csr);

    gemm_bf16<<<dim3(DD1 / 128, (NN + 127) / 128), 256, 0, stream>>>(xb, w1t, h1, NN, DD1, NF);
    attn_score<<<NN / 4, 256, 0, stream>>>(h1, at_s1, at_d1, asb, adb);
    attn_aggregate<1><<<NN, 256, 0, stream>>>(rowp, csr, asb, adb, h1, b1, bn1g, bn1b, bn1m, bn1v, (void*)h1p);

    gemm_bf16<<<dim3(DD1 / 128, (NN + 127) / 128), 256, 0, stream>>>(h1p, w2t, h1, NN, DD1, DD1);
    attn_score<<<NN / 4, 256, 0, stream>>>(h1, at_s2, at_d2, asb, adb);
    attn_aggregate<2><<<NN, 256, 0, stream>>>(rowp, csr, asb, adb, h1, b2, bn2g, bn2b, bn2m, bn2v, (void*)h2s);

    pool_kernel<<<(NN * OC) / 256, 256, 0, stream>>>(h2s, bat, sums, cnt);
    final_kernel<<<1, 128, 0, stream>>>(sums, cnt, linw, linb, out);
}